// Round 20
// baseline (69.722 us; speedup 1.0000x reference)
//
#include <hip/hip_runtime.h>
#include <hip/hip_bf16.h>
#include <cstdint>

#define B_    4
#define NH    8
#define N_TOK 2304
#define D_    32
#define C_    256
#define M_ROWS (B_ * N_TOK)   // 9216
#define KVB   64
#define NT2   (N_TOK / KVB)   // 36
#define M_FIX 10.0f           // fixed softmax max (exp2 domain); scores ~N(0,1.44), |s|<~9

typedef float  f32x4  __attribute__((ext_vector_type(4)));
typedef short  bf16x8 __attribute__((ext_vector_type(8)));

#define GLOADLDS(g, l) __builtin_amdgcn_global_load_lds( \
    (const __attribute__((address_space(1))) unsigned*)(g), \
    (__attribute__((address_space(3))) unsigned*)(l), 16, 0, 0)

static __device__ __forceinline__ unsigned short f2bf(float f) {
    union { float f; unsigned u; } v; v.f = f;
    unsigned u = v.u;
    u += 0x7FFF + ((u >> 16) & 1);   // round-to-nearest-even
    return (unsigned short)(u >> 16);
}

// hardware packed f32->bf16 (RTNE), lo = a, hi = b
static __device__ __forceinline__ unsigned cvt_pk_bf16(float a, float b) {
    unsigned r;
    asm("v_cvt_pk_bf16_f32 %0, %1, %2" : "=v"(r) : "v"(a), "v"(b));
    return r;
}

// ---------------- fused prep: X fp32->bf16 (blocks 0..2303) + W transpose (blocks 2304..2351) ----
__global__ void k_prep(const float* __restrict__ x,
                       const float* __restrict__ w0, const float* __restrict__ w1,
                       const float* __restrict__ w2,
                       unsigned short* __restrict__ xb, unsigned short* __restrict__ wt) {
    __shared__ float tile[64][65];
    int bid = blockIdx.x;
    if (bid < 2304) {
        int i = bid * 256 + threadIdx.x;      // one float4 per thread
        float4 v = reinterpret_cast<const float4*>(x)[i];
        ushort4 o;
        o.x = f2bf(v.x); o.y = f2bf(v.y); o.z = f2bf(v.z); o.w = f2bf(v.w);
        reinterpret_cast<ushort4*>(xb)[i] = o;
        return;
    }
    int t   = bid - 2304;           // 0..47
    int mat = t >> 4;  t &= 15;
    const float* w = (mat == 0) ? w0 : (mat == 1) ? w1 : w2;
    int tc  = (t & 3) * 64;         // c-tile base
    int td  = (t >> 2) * 64;        // d-tile base
    int tid = threadIdx.x;
    int r0  = tid >> 6;             // 0..3
    int x0  = tid & 63;
#pragma unroll
    for (int it = 0; it < 16; ++it) {
        int c = it * 4 + r0;
        tile[c][x0] = w[(tc + c) * C_ + td + x0];
    }
    __syncthreads();
    unsigned short* wto = wt + mat * (C_ * C_);
#pragma unroll
    for (int it = 0; it < 16; ++it) {
        int d = it * 4 + r0;
        wto[(td + d) * C_ + tc + x0] = f2bf(tile[x0][d]);
    }
}

// ---------------- QKV projection: LDS-staged MFMA GEMM 9216x768x256 ----------------
// grid (144, 6). Block: 64 rows x 128 cols; 4 waves 2x2, wave = 32x64 (2x4 frags).
// 3-stage pipeline, counted s_waitcnt vmcnt(3) + raw s_barrier.
// Q out: [bh][n][32].  K,V out: FRAGMENT-MAJOR (see k_attn).
__global__ __launch_bounds__(256) void k_proj(
    const unsigned short* __restrict__ xb,
    const unsigned short* __restrict__ wtb,
    const float* __restrict__ bq, const float* __restrict__ bk, const float* __restrict__ bv,
    unsigned short* __restrict__ qo, unsigned short* __restrict__ kfo, unsigned short* __restrict__ vfo)
{
    __shared__ __align__(16) unsigned short A_lds[3][64][32];    // 12 KB
    __shared__ __align__(16) unsigned short B_lds[3][128][32];   // 24 KB

    int rows0 = blockIdx.x * 64;
    int cols0 = blockIdx.y * 128;
    int mat   = cols0 >> 8;                   // constant per block (128 | 256)
    const float* bias = (mat == 0) ? bq : (mat == 1) ? bk : bv;
    float scale = (mat == 0) ? (0.17677669529663687f * 1.4426950408889634f) : 1.0f;

    int tid = threadIdx.x, wave = tid >> 6, lane = tid & 63;
    int lr = lane & 15, lg = lane >> 4;
    int wr = wave >> 1, wc = wave & 1;

    int srow = lane >> 2, sslot = lane & 3;
    int ra   = wave * 16 + srow;
    int keyA = ((ra >> 1) & 1) | (((ra >> 3) & 1) << 1);
    const unsigned short* asrc = xb + (rows0 + ra) * C_ + ((sslot ^ keyA) * 8);
    int rb   = wave * 32 + srow;
    int keyB0 = ((rb >> 1) & 1) | (((rb >> 3) & 1) << 1);
    int keyB1 = (((rb + 16) >> 1) & 1) | ((((rb + 16) >> 3) & 1) << 1);
    const unsigned short* bsrc0 = wtb + (cols0 + rb) * C_ + ((sslot ^ keyB0) * 8);
    const unsigned short* bsrc1 = wtb + (cols0 + rb + 16) * C_ + ((sslot ^ keyB1) * 8);

    char* aldsb = (char*)&A_lds[0][0][0];
    char* bldsb = (char*)&B_lds[0][0][0];
    int adst = wave * 1024;
    int bdst0 = wave * 2048, bdst1 = bdst0 + 1024;

    int xorb = (((lr >> 1) & 1) << 4) | (((lr >> 3) & 1) << 5);
    int fcol = (lg * 16) ^ xorb;
    int arow0 = wr * 32 + lr;
    int brow0 = wc * 64 + lr;

#define PSTAGE(ks, bidx) do {                               \
        int ko_ = (ks) * 32;                                \
        char* ad = aldsb + (bidx) * 4096;                   \
        char* bd = bldsb + (bidx) * 8192;                   \
        GLOADLDS(asrc + ko_, ad + adst);                    \
        GLOADLDS(bsrc0 + ko_, bd + bdst0);                  \
        GLOADLDS(bsrc1 + ko_, bd + bdst1);                  \
    } while (0)

    PSTAGE(0, 0);
    PSTAGE(1, 1);
    asm volatile("s_waitcnt vmcnt(3)" ::: "memory");
    __builtin_amdgcn_s_barrier();

    f32x4 acc[2][4];
#pragma unroll
    for (int i = 0; i < 2; ++i)
#pragma unroll
        for (int j = 0; j < 4; ++j) acc[i][j] = (f32x4){0.f, 0.f, 0.f, 0.f};

    int b0 = 0;
    for (int ks = 0; ks < 8; ++ks) {
        if (ks + 2 < 8) {
            int b2 = b0 + 2; if (b2 >= 3) b2 -= 3;
            PSTAGE(ks + 2, b2);
        }
        const char* ac = aldsb + b0 * 4096;
        const char* bc = bldsb + b0 * 8192;

        bf16x8 a[2], b[4];
#pragma unroll
        for (int fr = 0; fr < 2; ++fr)
            a[fr] = *reinterpret_cast<const bf16x8*>(ac + (arow0 + fr * 16) * 64 + fcol);
#pragma unroll
        for (int fn = 0; fn < 4; ++fn)
            b[fn] = *reinterpret_cast<const bf16x8*>(bc + (brow0 + fn * 16) * 64 + fcol);

        __builtin_amdgcn_s_setprio(1);
#pragma unroll
        for (int fr = 0; fr < 2; ++fr)
#pragma unroll
            for (int fn = 0; fn < 4; ++fn)
                acc[fr][fn] = __builtin_amdgcn_mfma_f32_16x16x32_bf16(a[fr], b[fn], acc[fr][fn], 0, 0, 0);
        __builtin_amdgcn_s_setprio(0);

        if (ks < 7) {
            if (ks + 2 < 8) asm volatile("s_waitcnt vmcnt(3)" ::: "memory");
            else            asm volatile("s_waitcnt vmcnt(0)" ::: "memory");
            __builtin_amdgcn_s_barrier();
        }
        b0 = (b0 + 1 == 3) ? 0 : b0 + 1;
    }
#undef PSTAGE

    int bidx = rows0 / N_TOK;
    int nb   = rows0 - bidx * N_TOK + wr * 32 + lg * 4;

    if (mat == 2) {
        // V fragment-major: chunk (bh, t, c=kseg*2+half), lane lV holds
        // V[d = half*16 + (lV&15)][t*64 + kseg*32 + (lV>>4)*8 + i], i=0..7.
#pragma unroll
        for (int fr = 0; fr < 2; ++fr)
#pragma unroll
            for (int fn = 0; fn < 4; ++fn) {
                int cm = (cols0 & 255) + wc * 64 + fn * 16 + lr;
                float bsv = bias[cm];
                int hh = cm >> 5, d = cm & 31;
                int bh = bidx * NH + hh;
                uint2 pr;
                pr.x = cvt_pk_bf16(acc[fr][fn][0] + bsv, acc[fr][fn][1] + bsv);
                pr.y = cvt_pk_bf16(acc[fr][fn][2] + bsv, acc[fr][fn][3] + bsv);
                int n0 = nb + fr * 16;
                int t = n0 >> 6, r = n0 & 63;
                int kseg = r >> 5, lgp = (r >> 3) & 3, i0 = r & 7;  // i0 in {0,4}
                int c = kseg * 2 + (d >> 4);
                int lV = lgp * 16 + (d & 15);
                *reinterpret_cast<uint2*>(vfo + ((bh * NT2 + t) * 4 + c) * 512 + lV * 8 + i0) = pr;
            }
    } else if (mat == 1) {
        // K fragment-major: chunk (bh, t, kt), lane l holds
        // K[t*64 + R(kt, l&15)][(l>>4)*8 + i], R(kt,m)=32(kt>>1)+4(kt&1)+8(m>>2)+(m&3).
#pragma unroll
        for (int fr = 0; fr < 2; ++fr)
#pragma unroll
            for (int fn = 0; fn < 4; ++fn) {
                int cm = (cols0 & 255) + wc * 64 + fn * 16 + lr;
                float bsv = bias[cm];
                int hh = cm >> 5, d = cm & 31;
                int bh = bidx * NH + hh;
#pragma unroll
                for (int j = 0; j < 4; ++j) {
                    int n = nb + fr * 16 + j;
                    int t = n >> 6, r = n & 63;
                    int kt  = ((r >> 5) << 1) | ((r >> 2) & 1);
                    int lr2 = ((r >> 3) & 3) * 4 + (r & 3);
                    int l   = (d >> 3) * 16 + lr2;
                    kfo[((bh * NT2 + t) * 4 + kt) * 512 + l * 8 + (d & 7)] =
                        f2bf(acc[fr][fn][j] + bsv);
                }
            }
    } else {
        unsigned short* dst = qo;
#pragma unroll
        for (int fr = 0; fr < 2; ++fr)
#pragma unroll
            for (int fn = 0; fn < 4; ++fn) {
                int cm = (cols0 & 255) + wc * 64 + fn * 16 + lr;
                float bsv = bias[cm];
                int hh = cm >> 5, d = cm & 31;
#pragma unroll
                for (int j = 0; j < 4; ++j) {
                    float val = (acc[fr][fn][j] + bsv) * scale;
                    dst[((bidx * NH + hh) * N_TOK + nb + fr * 16 + j) * D_ + d] = f2bf(val);
                }
            }
    }
}

// ---------------- fused flash attention + residual epilogue ----------------
// R19 base (barrier-free L2-direct, fragment-major K/V, 1 wave/block, grid
// 2304) with ONE change: the kv main loop is FORCED NON-UNROLLED.
// Hypothesis: with NT2 a literal, the compiler fully unrolled 36 iterations
// x ~100 instrs (incl. 20 MFMAs @ 8B) ~= 30-40 KB of code -> streams past the
// 32 KB L1 I$ every wave. That explains the 41us invariant across ALL data-
// path variants (R10..R19): every pipe <=40% busy, occupancy counter reads
// half nominal, and no data-side change moved the needle. A rolled loop body
// (~1 KB) is I$-resident; ring-copy v_movs (~32/iter) are noise vs the
// ~1200 stall cycles/tile observed.
__global__ __launch_bounds__(64, 4) void k_attn(
    const unsigned short* __restrict__ qb,
    const unsigned short* __restrict__ kf,    // fragment-major K
    const unsigned short* __restrict__ vf,    // fragment-major V
    const float* __restrict__ x,
    const float* __restrict__ gamma_p,
    float* __restrict__ out)
{
    // bijective XCD swizzle: 2304 workgroups, 8 XCDs, 288 per XCD
    int wid = (blockIdx.x & 7) * 288 + (blockIdx.x >> 3);
    int bh  = wid / 72;              // b*8 + head (72 waves per head)
    int qb0 = (wid % 72) * 32;

    int lane = threadIdx.x & 63;
    int lr = lane & 15, lg = lane >> 4;

    const unsigned short* Q  = qb + bh * N_TOK * D_;
    const unsigned short* Kb = kf + (size_t)bh * (NT2 * 4 * 512) + lane * 8;
    const unsigned short* Vb = vf + (size_t)bh * (NT2 * 4 * 512) + lane * 8;

    // Two Q fragments (B-operand): rows [qb0, +16) and [qb0+16, +16)
    int qrowA = qb0 + lr;
    bf16x8 qA = *reinterpret_cast<const bf16x8*>(Q + qrowA * D_ + lg * 8);
    bf16x8 qB = *reinterpret_cast<const bf16x8*>(Q + (qrowA + 16) * D_ + lg * 8);

#define LDK(dst, t, kt) dst = *reinterpret_cast<const bf16x8*>(Kb + ((t) * 4 + (kt)) * 512)
#define LDV(dst, t, c)  dst = *reinterpret_cast<const bf16x8*>(Vb + ((t) * 4 + (c)) * 512)

    // prologue: tile 0 fragments straight into registers
    bf16x8 kc0, kc1, kc2, kc3, vc0, vc1, vc2, vc3;
    LDK(kc0, 0, 0); LDK(kc1, 0, 1); LDK(kc2, 0, 2); LDK(kc3, 0, 3);
    LDV(vc0, 0, 0); LDV(vc1, 0, 1); LDV(vc2, 0, 2); LDV(vc3, 0, 3);

    f32x4 accA0 = (f32x4){0.f, 0.f, 0.f, 0.f};   // frag A: d = lr,    q = 4lg+j
    f32x4 accA1 = (f32x4){0.f, 0.f, 0.f, 0.f};   // frag A: d = 16+lr
    f32x4 accB0 = (f32x4){0.f, 0.f, 0.f, 0.f};   // frag B
    f32x4 accB1 = (f32x4){0.f, 0.f, 0.f, 0.f};
    f32x4 acclA = (f32x4){0.f, 0.f, 0.f, 0.f};   // l(q), frag A
    f32x4 acclB = (f32x4){0.f, 0.f, 0.f, 0.f};   // l(q), frag B

    union { unsigned w[4]; bf16x8 v; } ones;
    ones.w[0] = 0x3F803F80u; ones.w[1] = 0x3F803F80u;
    ones.w[2] = 0x3F803F80u; ones.w[3] = 0x3F803F80u;

    const f32x4 zinit = (f32x4){-M_FIX, -M_FIX, -M_FIX, -M_FIX};

#pragma clang loop unroll(disable)
    for (int t = 0; t < NT2; ++t) {
        // issue tile t+1's 8 coalesced loads; consumed a full iteration later
        bf16x8 kn0, kn1, kn2, kn3, vn0, vn1, vn2, vn3;
        if (t + 1 < NT2) {
            LDK(kn0, t + 1, 0); LDK(kn1, t + 1, 1); LDK(kn2, t + 1, 2); LDK(kn3, t + 1, 3);
            LDV(vn0, t + 1, 0); LDV(vn1, t + 1, 1); LDV(vn2, t + 1, 2); LDV(vn3, t + 1, 3);
        }

        // ---- S^T = K*Q - M : s[kt][j] = S[q=lr][32(kt>>1)+4(kt&1)+8lg+j] - M ----
        f32x4 sA[4], sB[4];
        __builtin_amdgcn_s_setprio(1);
        sA[0] = __builtin_amdgcn_mfma_f32_16x16x32_bf16(kc0, qA, zinit, 0, 0, 0);
        sB[0] = __builtin_amdgcn_mfma_f32_16x16x32_bf16(kc0, qB, zinit, 0, 0, 0);
        sA[1] = __builtin_amdgcn_mfma_f32_16x16x32_bf16(kc1, qA, zinit, 0, 0, 0);
        sB[1] = __builtin_amdgcn_mfma_f32_16x16x32_bf16(kc1, qB, zinit, 0, 0, 0);
        sA[2] = __builtin_amdgcn_mfma_f32_16x16x32_bf16(kc2, qA, zinit, 0, 0, 0);
        sB[2] = __builtin_amdgcn_mfma_f32_16x16x32_bf16(kc2, qB, zinit, 0, 0, 0);
        sA[3] = __builtin_amdgcn_mfma_f32_16x16x32_bf16(kc3, qA, zinit, 0, 0, 0);
        sB[3] = __builtin_amdgcn_mfma_f32_16x16x32_bf16(kc3, qB, zinit, 0, 0, 0);
        __builtin_amdgcn_s_setprio(0);

        // ---- per kseg: exp2 -> cvt_pk -> PV + l via MFMA (V-frags shared) ----
#pragma unroll
        for (int kseg = 0; kseg < 2; ++kseg) {
            union { unsigned w[4]; bf16x8 v; } paA, paB;
            paA.w[0] = cvt_pk_bf16(__builtin_amdgcn_exp2f(sA[2 * kseg][0]),
                                   __builtin_amdgcn_exp2f(sA[2 * kseg][1]));
            paA.w[1] = cvt_pk_bf16(__builtin_amdgcn_exp2f(sA[2 * kseg][2]),
                                   __builtin_amdgcn_exp2f(sA[2 * kseg][3]));
            paA.w[2] = cvt_pk_bf16(__builtin_amdgcn_exp2f(sA[2 * kseg + 1][0]),
                                   __builtin_amdgcn_exp2f(sA[2 * kseg + 1][1]));
            paA.w[3] = cvt_pk_bf16(__builtin_amdgcn_exp2f(sA[2 * kseg + 1][2]),
                                   __builtin_amdgcn_exp2f(sA[2 * kseg + 1][3]));
            paB.w[0] = cvt_pk_bf16(__builtin_amdgcn_exp2f(sB[2 * kseg][0]),
                                   __builtin_amdgcn_exp2f(sB[2 * kseg][1]));
            paB.w[1] = cvt_pk_bf16(__builtin_amdgcn_exp2f(sB[2 * kseg][2]),
                                   __builtin_amdgcn_exp2f(sB[2 * kseg][3]));
            paB.w[2] = cvt_pk_bf16(__builtin_amdgcn_exp2f(sB[2 * kseg + 1][0]),
                                   __builtin_amdgcn_exp2f(sB[2 * kseg + 1][1]));
            paB.w[3] = cvt_pk_bf16(__builtin_amdgcn_exp2f(sB[2 * kseg + 1][2]),
                                   __builtin_amdgcn_exp2f(sB[2 * kseg + 1][3]));
            bf16x8 vf0 = kseg ? vc2 : vc0;
            bf16x8 vf1 = kseg ? vc3 : vc1;
            accA0 = __builtin_amdgcn_mfma_f32_16x16x32_bf16(paA.v, vf0,    accA0, 0, 0, 0);
            accA1 = __builtin_amdgcn_mfma_f32_16x16x32_bf16(paA.v, vf1,    accA1, 0, 0, 0);
            accB0 = __builtin_amdgcn_mfma_f32_16x16x32_bf16(paB.v, vf0,    accB0, 0, 0, 0);
            accB1 = __builtin_amdgcn_mfma_f32_16x16x32_bf16(paB.v, vf1,    accB1, 0, 0, 0);
            acclA = __builtin_amdgcn_mfma_f32_16x16x32_bf16(paA.v, ones.v, acclA, 0, 0, 0);
            acclB = __builtin_amdgcn_mfma_f32_16x16x32_bf16(paB.v, ones.v, acclB, 0, 0, 0);
        }

        if (t + 1 < NT2) {
            kc0 = kn0; kc1 = kn1; kc2 = kn2; kc3 = kn3;
            vc0 = vn0; vc1 = vn1; vc2 = vn2; vc3 = vn3;
        }
    }
#undef LDK
#undef LDV

    // ---- epilogue: out = gamma * (O / l) + x, both q-frags ----
    float g = gamma_p[0];
    int b = bh >> 3, head = bh & 7;
#pragma unroll
    for (int j = 0; j < 4; ++j) {
        float linvA = 1.0f / acclA[j];
        float linvB = 1.0f / acclB[j];
        int nA = qb0 + 4 * lg + j;
        long rA = (long)(b * N_TOK + nA) * C_ + head * 32;
        long rB = rA + 16L * C_;
        out[rA + lr]      = g * (accA0[j] * linvA) + x[rA + lr];
        out[rA + 16 + lr] = g * (accA1[j] * linvA) + x[rA + 16 + lr];
        out[rB + lr]      = g * (accB0[j] * linvB) + x[rB + lr];
        out[rB + 16 + lr] = g * (accB1[j] * linvB) + x[rB + 16 + lr];
    }
}

extern "C" void kernel_launch(void* const* d_in, const int* in_sizes, int n_in,
                              void* d_out, int out_size, void* d_ws, size_t ws_size,
                              hipStream_t stream) {
    const float* x     = (const float*)d_in[0];
    const float* wq    = (const float*)d_in[1];
    const float* bq    = (const float*)d_in[2];
    const float* wk    = (const float*)d_in[3];
    const float* bk    = (const float*)d_in[4];
    const float* wv    = (const float*)d_in[5];
    const float* bv    = (const float*)d_in[6];
    const float* gamma = (const float*)d_in[7];
    float* out = (float*)d_out;

    char* ws = (char*)d_ws;
    unsigned short* xb   = (unsigned short*)(ws);                     // 9216*256*2  = 4718592
    unsigned short* wt   = (unsigned short*)(ws + 4718592);           // 3*256*256*2 = 393216
    unsigned short* qbuf = (unsigned short*)(ws + 5111808);           // 4718592
    unsigned short* kfb  = (unsigned short*)(ws + 9830400);           // 4718592 (fragment-major K)
    unsigned short* vfb  = (unsigned short*)(ws + 14548992);          // 4718592 (fragment-major V)

    k_prep<<<dim3(2352), dim3(256), 0, stream>>>(x, wq, wk, wv, xb, wt);
    k_proj<<<dim3(M_ROWS / 64, 6), dim3(256), 0, stream>>>(xb, wt, bq, bk, bv, qbuf, kfb, vfb);
    k_attn<<<dim3(N_TOK / 32 * B_ * NH), dim3(64), 0, stream>>>(qbuf, kfb, vfb, x, gamma, out);
}

// Round 21
// 58.616 us; speedup vs baseline: 1.1895x; 1.1895x over previous
//
#include <hip/hip_runtime.h>
#include <hip/hip_bf16.h>
#include <cstdint>

#define B_    4
#define NH    8
#define N_TOK 2304
#define D_    32
#define C_    256
#define M_ROWS (B_ * N_TOK)   // 9216
#define KVB   64
#define NT2   (N_TOK / KVB)   // 36
#define M_FIX 10.0f           // fixed softmax max (exp2 domain); scores ~N(0,1.44), |s|<~9

typedef float  f32x4  __attribute__((ext_vector_type(4)));
typedef short  bf16x8 __attribute__((ext_vector_type(8)));

#define GLOADLDS(g, l) __builtin_amdgcn_global_load_lds( \
    (const __attribute__((address_space(1))) unsigned*)(g), \
    (__attribute__((address_space(3))) unsigned*)(l), 16, 0, 0)

static __device__ __forceinline__ unsigned short f2bf(float f) {
    union { float f; unsigned u; } v; v.f = f;
    unsigned u = v.u;
    u += 0x7FFF + ((u >> 16) & 1);   // round-to-nearest-even
    return (unsigned short)(u >> 16);
}

// hardware packed f32->bf16 (RTNE), lo = a, hi = b
static __device__ __forceinline__ unsigned cvt_pk_bf16(float a, float b) {
    unsigned r;
    asm("v_cvt_pk_bf16_f32 %0, %1, %2" : "=v"(r) : "v"(a), "v"(b));
    return r;
}

// ---------------- fused prep: X fp32->bf16 (blocks 0..2303) + W transpose (blocks 2304..2351) ----
__global__ void k_prep(const float* __restrict__ x,
                       const float* __restrict__ w0, const float* __restrict__ w1,
                       const float* __restrict__ w2,
                       unsigned short* __restrict__ xb, unsigned short* __restrict__ wt) {
    __shared__ float tile[64][65];
    int bid = blockIdx.x;
    if (bid < 2304) {
        int i = bid * 256 + threadIdx.x;      // one float4 per thread
        float4 v = reinterpret_cast<const float4*>(x)[i];
        ushort4 o;
        o.x = f2bf(v.x); o.y = f2bf(v.y); o.z = f2bf(v.z); o.w = f2bf(v.w);
        reinterpret_cast<ushort4*>(xb)[i] = o;
        return;
    }
    int t   = bid - 2304;           // 0..47
    int mat = t >> 4;  t &= 15;
    const float* w = (mat == 0) ? w0 : (mat == 1) ? w1 : w2;
    int tc  = (t & 3) * 64;         // c-tile base
    int td  = (t >> 2) * 64;        // d-tile base
    int tid = threadIdx.x;
    int r0  = tid >> 6;             // 0..3
    int x0  = tid & 63;
#pragma unroll
    for (int it = 0; it < 16; ++it) {
        int c = it * 4 + r0;
        tile[c][x0] = w[(tc + c) * C_ + td + x0];
    }
    __syncthreads();
    unsigned short* wto = wt + mat * (C_ * C_);
#pragma unroll
    for (int it = 0; it < 16; ++it) {
        int d = it * 4 + r0;
        wto[(td + d) * C_ + tc + x0] = f2bf(tile[x0][d]);
    }
}

// ---------------- QKV projection: LDS-staged MFMA GEMM 9216x768x256 ----------------
// grid (144, 6). Block: 64 rows x 128 cols; 4 waves 2x2, wave = 32x64 (2x4 frags).
// 3-stage pipeline, counted s_waitcnt vmcnt(3) + raw s_barrier.
__global__ __launch_bounds__(256) void k_proj(
    const unsigned short* __restrict__ xb,
    const unsigned short* __restrict__ wtb,
    const float* __restrict__ bq, const float* __restrict__ bk, const float* __restrict__ bv,
    unsigned short* __restrict__ qo, unsigned short* __restrict__ ko, unsigned short* __restrict__ vto)
{
    __shared__ __align__(16) unsigned short A_lds[3][64][32];    // 12 KB
    __shared__ __align__(16) unsigned short B_lds[3][128][32];   // 24 KB

    int rows0 = blockIdx.x * 64;
    int cols0 = blockIdx.y * 128;
    int mat   = cols0 >> 8;                   // constant per block (128 | 256)
    const float* bias = (mat == 0) ? bq : (mat == 1) ? bk : bv;
    float scale = (mat == 0) ? (0.17677669529663687f * 1.4426950408889634f) : 1.0f;

    int tid = threadIdx.x, wave = tid >> 6, lane = tid & 63;
    int lr = lane & 15, lg = lane >> 4;
    int wr = wave >> 1, wc = wave & 1;

    int srow = lane >> 2, sslot = lane & 3;
    int ra   = wave * 16 + srow;
    int keyA = ((ra >> 1) & 1) | (((ra >> 3) & 1) << 1);
    const unsigned short* asrc = xb + (rows0 + ra) * C_ + ((sslot ^ keyA) * 8);
    int rb   = wave * 32 + srow;
    int keyB0 = ((rb >> 1) & 1) | (((rb >> 3) & 1) << 1);
    int keyB1 = (((rb + 16) >> 1) & 1) | ((((rb + 16) >> 3) & 1) << 1);
    const unsigned short* bsrc0 = wtb + (cols0 + rb) * C_ + ((sslot ^ keyB0) * 8);
    const unsigned short* bsrc1 = wtb + (cols0 + rb + 16) * C_ + ((sslot ^ keyB1) * 8);

    char* aldsb = (char*)&A_lds[0][0][0];
    char* bldsb = (char*)&B_lds[0][0][0];
    int adst = wave * 1024;
    int bdst0 = wave * 2048, bdst1 = bdst0 + 1024;

    int xorb = (((lr >> 1) & 1) << 4) | (((lr >> 3) & 1) << 5);
    int fcol = (lg * 16) ^ xorb;
    int arow0 = wr * 32 + lr;
    int brow0 = wc * 64 + lr;

#define PSTAGE(ks, bidx) do {                               \
        int ko_ = (ks) * 32;                                \
        char* ad = aldsb + (bidx) * 4096;                   \
        char* bd = bldsb + (bidx) * 8192;                   \
        GLOADLDS(asrc + ko_, ad + adst);                    \
        GLOADLDS(bsrc0 + ko_, bd + bdst0);                  \
        GLOADLDS(bsrc1 + ko_, bd + bdst1);                  \
    } while (0)

    // prologue: stage K-steps 0,1; wait step 0 landed (step 1 in flight)
    PSTAGE(0, 0);
    PSTAGE(1, 1);
    asm volatile("s_waitcnt vmcnt(3)" ::: "memory");
    __builtin_amdgcn_s_barrier();

    f32x4 acc[2][4];
#pragma unroll
    for (int i = 0; i < 2; ++i)
#pragma unroll
        for (int j = 0; j < 4; ++j) acc[i][j] = (f32x4){0.f, 0.f, 0.f, 0.f};

    int b0 = 0;
    for (int ks = 0; ks < 8; ++ks) {
        if (ks + 2 < 8) {
            int b2 = b0 + 2; if (b2 >= 3) b2 -= 3;
            PSTAGE(ks + 2, b2);
        }
        const char* ac = aldsb + b0 * 4096;
        const char* bc = bldsb + b0 * 8192;

        bf16x8 a[2], b[4];
#pragma unroll
        for (int fr = 0; fr < 2; ++fr)
            a[fr] = *reinterpret_cast<const bf16x8*>(ac + (arow0 + fr * 16) * 64 + fcol);
#pragma unroll
        for (int fn = 0; fn < 4; ++fn)
            b[fn] = *reinterpret_cast<const bf16x8*>(bc + (brow0 + fn * 16) * 64 + fcol);

        __builtin_amdgcn_s_setprio(1);
#pragma unroll
        for (int fr = 0; fr < 2; ++fr)
#pragma unroll
            for (int fn = 0; fn < 4; ++fn)
                acc[fr][fn] = __builtin_amdgcn_mfma_f32_16x16x32_bf16(a[fr], b[fn], acc[fr][fn], 0, 0, 0);
        __builtin_amdgcn_s_setprio(0);

        if (ks < 7) {
            if (ks + 2 < 8) asm volatile("s_waitcnt vmcnt(3)" ::: "memory");
            else            asm volatile("s_waitcnt vmcnt(0)" ::: "memory");
            __builtin_amdgcn_s_barrier();
        }
        b0 = (b0 + 1 == 3) ? 0 : b0 + 1;
    }
#undef PSTAGE

    int bidx = rows0 / N_TOK;
    int nb   = rows0 - bidx * N_TOK + wr * 32 + lg * 4;

    if (mat == 2) {
#pragma unroll
        for (int fr = 0; fr < 2; ++fr)
#pragma unroll
            for (int fn = 0; fn < 4; ++fn) {
                int cm = (cols0 & 255) + wc * 64 + fn * 16 + lr;
                float bsv = bias[cm];
                int hh = cm >> 5, d = cm & 31;
                uint2 pr;
                pr.x = cvt_pk_bf16(acc[fr][fn][0] + bsv, acc[fr][fn][1] + bsv);
                pr.y = cvt_pk_bf16(acc[fr][fn][2] + bsv, acc[fr][fn][3] + bsv);
                *reinterpret_cast<uint2*>(vto + ((bidx * NH + hh) * D_ + d) * N_TOK + nb + fr * 16) = pr;
            }
    } else {
        unsigned short* dst = (mat == 0) ? qo : ko;
#pragma unroll
        for (int fr = 0; fr < 2; ++fr)
#pragma unroll
            for (int fn = 0; fn < 4; ++fn) {
                int cm = (cols0 & 255) + wc * 64 + fn * 16 + lr;
                float bsv = bias[cm];
                int hh = cm >> 5, d = cm & 31;
#pragma unroll
                for (int j = 0; j < 4; ++j) {
                    float val = (acc[fr][fn][j] + bsv) * scale;
                    dst[((bidx * NH + hh) * N_TOK + nb + fr * 16 + j) * D_ + d] = f2bf(val);
                }
            }
    }
}

// ---------------- fused flash attention + residual epilogue ----------------
// Best measured configuration (R13, 58.4 us total): 4 waves / 256 threads,
// 2 q-frags per wave (32 q), 128 q/block, grid 576. KVB=64: 24 KB LDS ring,
// ~90 VGPR -> 16 waves/CU. Waves 0-1 stage K, waves 2-3 stage Vt — 2
// global_load_lds per wave per tile -> counted s_waitcnt vmcnt(2), 3-stage
// ring, never drain mid-loop. Swapped QK^T with PERMUTED K rows (s IS the
// PV A-fragment); FIXED-MAX softmax (C-init = -M_FIX); row-sums l via MFMA
// with B=ones. NOTE: attn has a ~41us floor invariant to occupancy, LDS vs
// L2-direct, barriers, grid balance, exp pipe, I$ (10 falsified theories,
// R10-R20); all pipe counters <=40% — stall source not visible in the
// gfx950 counter set. This is the best-known configuration.
__global__ __launch_bounds__(256, 4) void k_attn(
    const unsigned short* __restrict__ qb,
    const unsigned short* __restrict__ kb,
    const unsigned short* __restrict__ vtg,   // [bh][32][2304]
    const float* __restrict__ x,
    const float* __restrict__ gamma_p,
    float* __restrict__ out)
{
    __shared__ __align__(16) unsigned short K_lds[3][KVB][32];    // 12 KB
    __shared__ __align__(16) unsigned short Vt_lds[3][32][KVB];   // 12 KB

    // bijective XCD swizzle: 576 workgroups, 8 XCDs, 72 per XCD
    int wid = (blockIdx.x & 7) * 72 + (blockIdx.x >> 3);
    int bh  = wid / 18;              // b*8 + head
    int qb0 = (wid % 18) * 128;

    int tid = threadIdx.x, wave = tid >> 6, lane = tid & 63;
    int lr = lane & 15, lg = lane >> 4;

    const unsigned short* Q  = qb  + bh * N_TOK * D_;
    const unsigned short* K  = kb  + bh * N_TOK * D_;
    const unsigned short* Vt = vtg + bh * D_ * N_TOK;

    // Two Q fragments (B-operand): rows [wave*32, +16) and [wave*32+16, +16)
    int qrowA = qb0 + wave * 32 + lr;
    bf16x8 qA = *reinterpret_cast<const bf16x8*>(Q + qrowA * D_ + lg * 8);
    bf16x8 qB = *reinterpret_cast<const bf16x8*>(Q + (qrowA + 16) * D_ + lg * 8);

    // ---- staging: waves 0-1 stage K (rows 32w..32w+31, 2 x 1KB chunks);
    //      waves 2-3 stage Vt (rows 16vw..16vw+15, 2 x 1KB chunks of 8 rows) ----
    bool stK = wave < 2;
    // K: chunk rows 16c..16c+15, lane -> (row = 16c + (lane>>2), 16B slot lane&3)
    int kr0   = 32 * wave + (lane >> 2);
    int kslot = ((kr0 >> 1) & 1) | (((kr0 >> 3) & 1) << 1);   // same for kr0+16
    int koff0 = kr0 * D_ + (((lane & 3) ^ kslot) * 8);
    int koff1 = koff0 + 16 * D_;
    int kdst0 = wave * 2048 + lane * 16;
    int kdst1 = kdst0 + 1024;
    // Vt: row stride 128 B; chunk = 8 rows; lane -> (row = 8c + (lane>>3), slot lane&7)
    int vw    = wave - 2;
    int vr0   = 16 * vw + (lane >> 3);
    int vkeyw = vr0 & 7;                                      // same for vr0+8
    int voff0 = vr0 * N_TOK + (((lane & 7) ^ vkeyw) * 8);
    int voff1 = (vr0 + 8) * N_TOK + (((lane & 7) ^ vkeyw) * 8);
    int vdst0 = vw * 2048 + lane * 16;
    int vdst1 = vdst0 + 1024;

    char* kldsb = (char*)&K_lds[0][0][0];
    char* vldsb = (char*)&Vt_lds[0][0][0];

#define STAGE(st, bidx) do {                                    \
        if (stK) {                                              \
            const unsigned short* Kn = K + (st) * (KVB * D_);   \
            char* kd = kldsb + (bidx) * 4096;                   \
            GLOADLDS(Kn + koff0, kd + kdst0);                   \
            GLOADLDS(Kn + koff1, kd + kdst1);                   \
        } else {                                                \
            const unsigned short* Vn = Vt + (st) * KVB;         \
            char* vd = vldsb + (bidx) * 4096;                   \
            GLOADLDS(Vn + voff0, vd + vdst0);                   \
            GLOADLDS(Vn + voff1, vd + vdst1);                   \
        } } while (0)

    // prologue: stage tiles 0,1; ensure tile 0 landed (tile 1 stays in flight)
    STAGE(0, 0);
    STAGE(1, 1);
    asm volatile("s_waitcnt vmcnt(2)" ::: "memory");
    __builtin_amdgcn_s_barrier();

    f32x4 accA0 = (f32x4){0.f, 0.f, 0.f, 0.f};   // frag A: d = lr,    q = 4lg+j
    f32x4 accA1 = (f32x4){0.f, 0.f, 0.f, 0.f};   // frag A: d = 16+lr
    f32x4 accB0 = (f32x4){0.f, 0.f, 0.f, 0.f};   // frag B
    f32x4 accB1 = (f32x4){0.f, 0.f, 0.f, 0.f};
    f32x4 acclA = (f32x4){0.f, 0.f, 0.f, 0.f};   // l(q), frag A
    f32x4 acclB = (f32x4){0.f, 0.f, 0.f, 0.f};   // l(q), frag B

    union { unsigned w[4]; bf16x8 v; } ones;
    ones.w[0] = 0x3F803F80u; ones.w[1] = 0x3F803F80u;
    ones.w[2] = 0x3F803F80u; ones.w[3] = 0x3F803F80u;

    // K read: row R(kt,lr) swizzled; per-lane part precomputed
    int kread_key = (((lr >> 1) & 1) << 4) | (((lr >> 2) & 1) << 5);
    int krow_lane = (8 * (lr >> 2) + (lr & 3)) * 64 + ((lg * 16) ^ kread_key);
    int vkey = (lr & 7) << 4;

    const f32x4 zinit = (f32x4){-M_FIX, -M_FIX, -M_FIX, -M_FIX};

    int b0 = 0;   // buffer holding tile t
    for (int t = 0; t < NT2; ++t) {
        // issue tile t+2; its loads stay in flight across the barrier
        if (t + 2 < NT2) {
            int b2 = b0 + 2; if (b2 >= 3) b2 -= 3;
            STAGE(t + 2, b2);
        }
        const char* kc = kldsb + b0 * 4096;
        const char* vc = vldsb + b0 * 4096;

        // ---- S^T = K*Q - M : s[kt][j] = S[q=lr][32(kt>>1)+4(kt&1)+8lg+j] - M ----
        f32x4 sA[4], sB[4];
        __builtin_amdgcn_s_setprio(1);
#pragma unroll
        for (int kt = 0; kt < 4; ++kt) {
            bf16x8 kf = *reinterpret_cast<const bf16x8*>(
                kc + (kt >> 1) * 2048 + (kt & 1) * 256 + krow_lane);
            sA[kt] = __builtin_amdgcn_mfma_f32_16x16x32_bf16(kf, qA, zinit, 0, 0, 0);
            sB[kt] = __builtin_amdgcn_mfma_f32_16x16x32_bf16(kf, qB, zinit, 0, 0, 0);
        }
        __builtin_amdgcn_s_setprio(0);

        // ---- per kseg: exp2 -> cvt_pk -> PV; V-frag reads SHARED by both q-frags ----
#pragma unroll
        for (int kseg = 0; kseg < 2; ++kseg) {
            union { unsigned w[4]; bf16x8 v; } paA, paB;
            paA.w[0] = cvt_pk_bf16(__builtin_amdgcn_exp2f(sA[2 * kseg][0]),
                                   __builtin_amdgcn_exp2f(sA[2 * kseg][1]));
            paA.w[1] = cvt_pk_bf16(__builtin_amdgcn_exp2f(sA[2 * kseg][2]),
                                   __builtin_amdgcn_exp2f(sA[2 * kseg][3]));
            paA.w[2] = cvt_pk_bf16(__builtin_amdgcn_exp2f(sA[2 * kseg + 1][0]),
                                   __builtin_amdgcn_exp2f(sA[2 * kseg + 1][1]));
            paA.w[3] = cvt_pk_bf16(__builtin_amdgcn_exp2f(sA[2 * kseg + 1][2]),
                                   __builtin_amdgcn_exp2f(sA[2 * kseg + 1][3]));
            paB.w[0] = cvt_pk_bf16(__builtin_amdgcn_exp2f(sB[2 * kseg][0]),
                                   __builtin_amdgcn_exp2f(sB[2 * kseg][1]));
            paB.w[1] = cvt_pk_bf16(__builtin_amdgcn_exp2f(sB[2 * kseg][2]),
                                   __builtin_amdgcn_exp2f(sB[2 * kseg][3]));
            paB.w[2] = cvt_pk_bf16(__builtin_amdgcn_exp2f(sB[2 * kseg + 1][0]),
                                   __builtin_amdgcn_exp2f(sB[2 * kseg + 1][1]));
            paB.w[3] = cvt_pk_bf16(__builtin_amdgcn_exp2f(sB[2 * kseg + 1][2]),
                                   __builtin_amdgcn_exp2f(sB[2 * kseg + 1][3]));
            int off = (kseg * 64 + lg * 16) ^ vkey;
            bf16x8 vf0 = *reinterpret_cast<const bf16x8*>(vc + lr * 128 + off);
            bf16x8 vf1 = *reinterpret_cast<const bf16x8*>(vc + (16 + lr) * 128 + off);
            accA0 = __builtin_amdgcn_mfma_f32_16x16x32_bf16(paA.v, vf0,    accA0, 0, 0, 0);
            accA1 = __builtin_amdgcn_mfma_f32_16x16x32_bf16(paA.v, vf1,    accA1, 0, 0, 0);
            accB0 = __builtin_amdgcn_mfma_f32_16x16x32_bf16(paB.v, vf0,    accB0, 0, 0, 0);
            accB1 = __builtin_amdgcn_mfma_f32_16x16x32_bf16(paB.v, vf1,    accB1, 0, 0, 0);
            acclA = __builtin_amdgcn_mfma_f32_16x16x32_bf16(paA.v, ones.v, acclA, 0, 0, 0);
            acclB = __builtin_amdgcn_mfma_f32_16x16x32_bf16(paB.v, ones.v, acclB, 0, 0, 0);
        }

        // counted wait: L(t+1) landed; L(t+2) stays in flight.
        if (t < NT2 - 1) {
            if (t + 2 < NT2) asm volatile("s_waitcnt vmcnt(2)" ::: "memory");
            else             asm volatile("s_waitcnt vmcnt(0)" ::: "memory");
            __builtin_amdgcn_s_barrier();
        }
        b0 = (b0 + 1 == 3) ? 0 : b0 + 1;
    }
#undef STAGE

    // ---- epilogue: out = gamma * (O / l) + x, both q-frags ----
    float g = gamma_p[0];
    int b = bh >> 3, head = bh & 7;
#pragma unroll
    for (int j = 0; j < 4; ++j) {
        float linvA = 1.0f / acclA[j];
        float linvB = 1.0f / acclB[j];
        int nA = qb0 + wave * 32 + 4 * lg + j;
        long rA = (long)(b * N_TOK + nA) * C_ + head * 32;
        long rB = rA + 16L * C_;
        out[rA + lr]      = g * (accA0[j] * linvA) + x[rA + lr];
        out[rA + 16 + lr] = g * (accA1[j] * linvA) + x[rA + 16 + lr];
        out[rB + lr]      = g * (accB0[j] * linvB) + x[rB + lr];
        out[rB + 16 + lr] = g * (accB1[j] * linvB) + x[rB + 16 + lr];
    }
}

extern "C" void kernel_launch(void* const* d_in, const int* in_sizes, int n_in,
                              void* d_out, int out_size, void* d_ws, size_t ws_size,
                              hipStream_t stream) {
    const float* x     = (const float*)d_in[0];
    const float* wq    = (const float*)d_in[1];
    const float* bq    = (const float*)d_in[2];
    const float* wk    = (const float*)d_in[3];
    const float* bk    = (const float*)d_in[4];
    const float* wv    = (const float*)d_in[5];
    const float* bv    = (const float*)d_in[6];
    const float* gamma = (const float*)d_in[7];
    float* out = (float*)d_out;

    char* ws = (char*)d_ws;
    unsigned short* xb   = (unsigned short*)(ws);                     // 9216*256*2  = 4718592
    unsigned short* wt   = (unsigned short*)(ws + 4718592);           // 3*256*256*2 = 393216
    unsigned short* qbuf = (unsigned short*)(ws + 5111808);           // 4718592
    unsigned short* kbuf = (unsigned short*)(ws + 9830400);           // 4718592
    unsigned short* vtg  = (unsigned short*)(ws + 14548992);          // 4718592 (V transposed)

    k_prep<<<dim3(2352), dim3(256), 0, stream>>>(x, wq, wk, wv, xb, wt);
    k_proj<<<dim3(M_ROWS / 64, 6), dim3(256), 0, stream>>>(xb, wt, bq, bk, bv, qbuf, kbuf, vtg);
    k_attn<<<dim3(N_TOK / 128 * B_ * NH), dim3(256), 0, stream>>>(qbuf, kbuf, vtg, x, gamma, out);
}